// Round 7
// baseline (548.803 us; speedup 1.0000x reference)
//
#include <hip/hip_runtime.h>

#define B_   4
#define S_   1024
#define D_   1024
#define H_   16
#define HD_  64

typedef __bf16 bf16_t;
typedef __attribute__((ext_vector_type(8))) __bf16 bf16x8;
typedef __attribute__((ext_vector_type(4))) float f32x4;

#define MFMA16(a, b, c) __builtin_amdgcn_mfma_f32_16x16x32_bf16((a), (b), (c), 0, 0, 0)

__device__ inline unsigned short f2bf(float f) {
    unsigned int u = __builtin_bit_cast(unsigned int, f);
    u += 0x7FFFu + ((u >> 16) & 1u);   // RNE
    return (unsigned short)(u >> 16);
}

__device__ inline bf16x8 ld_frag(const unsigned short* p) {
    uint4 u = *(const uint4*)p;
    return __builtin_bit_cast(bf16x8, u);
}

// ---------------------------------------------------------------------------
// Fused preprocessing (single launch, flattened 1D grid):
//   blocks [0, 4096)          : x fp32 -> bf16 (one float4/thread)
//   blocks [4096, 4096+768)   : W_qkv [1024][3072] -> wqkvt [3072][1024] bf16
//   blocks [4864, 4864+256)   : W_o   [1024][1024] -> wot   [1024][1024] bf16
// ---------------------------------------------------------------------------
__global__ __launch_bounds__(256) void preprocess(
    const float* __restrict__ x,     unsigned short* __restrict__ x_bf,
    const float* __restrict__ W_qkv, unsigned short* __restrict__ wqkvt,
    const float* __restrict__ W_o,   unsigned short* __restrict__ wot)
{
    __shared__ float T[64][65];
    const int tid = threadIdx.x;
    int bid = blockIdx.x;

    if (bid < 4096) {
        const size_t idx = (size_t)bid * 256 + tid;
        float4 v = *(const float4*)(x + idx * 4);
        ushort4 r;
        r.x = f2bf(v.x); r.y = f2bf(v.y); r.z = f2bf(v.z); r.w = f2bf(v.w);
        *(ushort4*)(x_bf + idx * 4) = r;
        return;
    }
    bid -= 4096;
    const float* in; unsigned short* out; int N, bx, by;
    if (bid < 768) { in = W_qkv; out = wqkvt; N = 3072; bx = bid % 48; by = bid / 48; }
    else { bid -= 768; in = W_o; out = wot; N = 1024; bx = bid % 16; by = bid / 16; }
    const int K = 1024;
    const int k0 = by * 64, n0 = bx * 64;
#pragma unroll
    for (int i = 0; i < 4; ++i) {
        int c = tid + i * 256;
        int row = c >> 4, col = (c & 15) << 2;
        float4 v = *(const float4*)(in + (size_t)(k0 + row) * N + n0 + col);
        T[row][col + 0] = v.x; T[row][col + 1] = v.y;
        T[row][col + 2] = v.z; T[row][col + 3] = v.w;
    }
    __syncthreads();
#pragma unroll
    for (int i = 0; i < 4; ++i) {
        int c = tid + i * 256;
        int nr = c >> 4, kc = (c & 15) << 2;
        ushort4 r;
        r.x = f2bf(T[kc + 0][nr]); r.y = f2bf(T[kc + 1][nr]);
        r.z = f2bf(T[kc + 2][nr]); r.w = f2bf(T[kc + 3][nr]);
        *(ushort4*)(out + (size_t)(n0 + nr) * K + k0 + kc) = r;
    }
}

// ---------------------------------------------------------------------------
// bf16 transpose of V into per-(b,h) key-major layout:
// v [4096][1024] (col = h*64+dim)  ->  vt [bh][dim][key].
// Grid (S/64, B*H), 256 threads.
// ---------------------------------------------------------------------------
__global__ __launch_bounds__(256) void transpose_v_bf16(
    const unsigned short* __restrict__ v,
    unsigned short* __restrict__ vt)
{
    __shared__ unsigned short T[64][65];
    const int tid = threadIdx.x;
    const int kt = blockIdx.x, bh = blockIdx.y;
    const int b = bh >> 4, h = bh & 15;
#pragma unroll
    for (int i = 0; i < 2; ++i) {
        const int c = tid + i * 256;
        const int key = c >> 3, off = (c & 7) << 3;
        uint4 u = *(const uint4*)(v + (size_t)(b * 1024 + kt * 64 + key) * 1024 + h * 64 + off);
        union { uint4 u4; unsigned short us[8]; } uu; uu.u4 = u;
#pragma unroll
        for (int t = 0; t < 8; ++t) T[key][off + t] = uu.us[t];
    }
    __syncthreads();
#pragma unroll
    for (int i = 0; i < 16; ++i) {
        const int c = tid + i * 256;          // 0..4095
        const int dim = c >> 6, key = c & 63;
        vt[((size_t)bh * 64 + dim) * 1024 + kt * 64 + key] = T[key][dim];
    }
}

// ---------------------------------------------------------------------------
// bf16 MFMA GEMM: C[M,N] = A[M,K] @ Bt[N,K]^T + bias.
// 128x128 tile, 4 waves (2x2). Reg-staged into padded LDS [128][72]
// (conflict-free ds_read), with T14 async-STAGE split: next K-tile's global
// loads are ISSUED right after barrier-1 (fly during the 32-MFMA compute
// phase) and ds_written at the top of the next iteration (m249: +3%).
// MODE 0 (QKV): q (pre-scaled 1/8), k -> qk[row][head*128 + 0..127];
//               v -> vnat[row][head*64+dim] (coalesced; transposed later).
// MODE 1: fp32 out[M][N].
// ---------------------------------------------------------------------------
template<int MODE>
__global__ __launch_bounds__(256) void gemm_bf16(
    const unsigned short* __restrict__ A,
    const unsigned short* __restrict__ Bt,
    const float* __restrict__ bias,
    unsigned short* __restrict__ qk,
    unsigned short* __restrict__ vnat,
    float* __restrict__ out,
    int K, int N)
{
    __shared__ unsigned short Alds[128][72];
    __shared__ unsigned short Blds[128][72];
    const int tid  = threadIdx.x;
    const int l    = tid & 63, w = tid >> 6;
    const int wm   = w >> 1, wn = w & 1;
    const int quad = l >> 4, n16 = l & 15;
    const int bm = blockIdx.y * 128, bn = blockIdx.x * 128;

    const int soff = (tid & 7) << 3;    // staging ushort col (same for all i)
    const int row0 = tid >> 3;          // staging row, +i*32

    const f32x4 zero4 = {0.f, 0.f, 0.f, 0.f};
    f32x4 acc[4][4];
#pragma unroll
    for (int i = 0; i < 4; ++i)
#pragma unroll
        for (int j = 0; j < 4; ++j) acc[i][j] = zero4;

    // prologue: stage K-tile 0 into regs
    uint4 pa[4], pb[4];
#pragma unroll
    for (int i = 0; i < 4; ++i) {
        pa[i] = *(const uint4*)(A  + (size_t)(bm + row0 + i * 32) * K + soff);
        pb[i] = *(const uint4*)(Bt + (size_t)(bn + row0 + i * 32) * K + soff);
    }

    for (int k0 = 0; k0 < K; k0 += 64) {
        // write staged regs (loaded ~1 compute-phase ago) to LDS
#pragma unroll
        for (int i = 0; i < 4; ++i) {
            *(uint4*)&Alds[row0 + i * 32][soff] = pa[i];
            *(uint4*)&Blds[row0 + i * 32][soff] = pb[i];
        }
        __syncthreads();
        // issue next tile's loads EARLY — latency hides under the MFMAs
        if (k0 + 64 < K) {
#pragma unroll
            for (int i = 0; i < 4; ++i) {
                pa[i] = *(const uint4*)(A  + (size_t)(bm + row0 + i * 32) * K + k0 + 64 + soff);
                pb[i] = *(const uint4*)(Bt + (size_t)(bn + row0 + i * 32) * K + k0 + 64 + soff);
            }
        }
#pragma unroll
        for (int kk = 0; kk < 2; ++kk) {
            const int kc = kk * 32 + quad * 8;
            bf16x8 af[4], bfv[4];
#pragma unroll
            for (int i = 0; i < 4; ++i) af[i]  = ld_frag(&Alds[wm * 64 + i * 16 + n16][kc]);
#pragma unroll
            for (int j = 0; j < 4; ++j) bfv[j] = ld_frag(&Blds[wn * 64 + j * 16 + n16][kc]);
#pragma unroll
            for (int i = 0; i < 4; ++i)
#pragma unroll
                for (int j = 0; j < 4; ++j)
                    acc[i][j] = MFMA16(af[i], bfv[j], acc[i][j]);
        }
        __syncthreads();
    }

    // epilogue
#pragma unroll
    for (int j = 0; j < 4; ++j) {
        const int col0 = bn + wn * 64 + j * 16;
        const int col  = col0 + n16;
        const float bv = bias ? bias[col] : 0.f;
        if (MODE == 0) {
            const int head = col0 / 192;
            const int rem  = col0 % 192;
            if (rem < 128) {
                // q columns (rem<64) carry the 1/sqrt(hd) logit scale so
                // attn_fused skips the per-logit multiply (exact in bf16).
                const float sc = (rem < 64) ? 0.125f : 1.0f;
#pragma unroll
                for (int i = 0; i < 4; ++i)
#pragma unroll
                    for (int r = 0; r < 4; ++r) {
                        int row = bm + wm * 64 + i * 16 + quad * 4 + r;
                        qk[(size_t)row * 2048 + head * 128 + rem + n16] =
                            f2bf((acc[i][j][r] + bv) * sc);
                    }
            } else {
                const int dcol = head * 64 + (rem - 128) + n16;
#pragma unroll
                for (int i = 0; i < 4; ++i)
#pragma unroll
                    for (int r = 0; r < 4; ++r) {
                        int row = bm + wm * 64 + i * 16 + quad * 4 + r;
                        vnat[(size_t)row * 1024 + dcol] = f2bf(acc[i][j][r] + bv);
                    }
            }
        } else {
#pragma unroll
            for (int i = 0; i < 4; ++i)
#pragma unroll
                for (int r = 0; r < 4; ++r) {
                    int row = bm + wm * 64 + i * 16 + quad * 4 + r;
                    out[(size_t)row * N + col] = acc[i][j][r] + bv;
                }
        }
    }
}

// ---------------------------------------------------------------------------
// Fused attention (EXACT R5 session-best structure): per block = 16 Q-rows
// of one (b,h). 4 waves. Wave-private K/V staging (wave w consumes only
// rows/dims w*16..+15), phases 1/3 barrier-free (in-wave lgkmcnt ordering).
// Depth-1 pipelined: load(s+1)->regs, ds_read+MFMA(s), ds_write(s+1).
// Barriers: 2 (softmax reductions) + 1 (P handoff). Grid (S/16, B*H).
// ---------------------------------------------------------------------------
__global__ __launch_bounds__(256) void attn_fused(
    const unsigned short* __restrict__ qk,   // [4096][2048]
    const unsigned short* __restrict__ vt,   // [64][64][1024]
    float* __restrict__ attn,                // [64][1024][1024]
    unsigned short* __restrict__ values)     // [4096][1024]
{
    __shared__ unsigned short KVw[4][2][16][72];   // [wave][buf][row][col]
    __shared__ unsigned short Plds[16][1032];
    __shared__ float redbuf[2][4][16];

    const int qb = blockIdx.x, bh = blockIdx.y;
    const int b = bh >> 4, h = bh & 15;
    const int tid = threadIdx.x, l = tid & 63, w = tid >> 6;
    const int quad = l >> 4, n16 = l & 15;

    const int prow = l >> 3;            // 0..7
    const int poff = (l & 7) << 3;      // 0..56 (ushort col)

    // preload Q A-frags (q already scaled by 1/8 in gemm<0> epilogue)
    bf16x8 qf[2];
    {
        const unsigned short* qbase =
            qk + (size_t)(b * 1024 + qb * 16 + n16) * 2048 + h * 128 + quad * 8;
        qf[0] = ld_frag(qbase);
        qf[1] = ld_frag(qbase + 32);
    }

    const f32x4 zero4 = {0.f, 0.f, 0.f, 0.f};
    f32x4 c[16];
#pragma unroll
    for (int s = 0; s < 16; ++s) c[s] = zero4;

    // ---- Phase 1: QK^T, wave-private dbuf staging, barrier-free ----
    const unsigned short* kwbase =
        qk + (size_t)(b * 1024 + w * 16) * 2048 + h * 128 + 64;
    {
        uint4 r0 = *(const uint4*)(kwbase + (size_t)prow * 2048 + poff);
        uint4 r1 = *(const uint4*)(kwbase + (size_t)(prow + 8) * 2048 + poff);
        *(uint4*)&KVw[w][0][prow][poff]     = r0;
        *(uint4*)&KVw[w][0][prow + 8][poff] = r1;
    }
    for (int s = 0; s < 16; ++s) {
        uint4 n0, n1;
        if (s < 15) {
            const unsigned short* p = kwbase + (size_t)(s + 1) * 64 * 2048;
            n0 = *(const uint4*)(p + (size_t)prow * 2048 + poff);
            n1 = *(const uint4*)(p + (size_t)(prow + 8) * 2048 + poff);
        }
        const int pb = s & 1;
        bf16x8 k0f = ld_frag(&KVw[w][pb][n16][quad * 8]);
        bf16x8 k1f = ld_frag(&KVw[w][pb][n16][32 + quad * 8]);
        c[s] = MFMA16(qf[0], k0f, c[s]);
        c[s] = MFMA16(qf[1], k1f, c[s]);
        if (s < 15) {
            *(uint4*)&KVw[w][pb ^ 1][prow][poff]     = n0;
            *(uint4*)&KVw[w][pb ^ 1][prow + 8][poff] = n1;
        }
    }

    // ---- Phase 2: softmax in registers ----
    float mx[4] = {-1e30f, -1e30f, -1e30f, -1e30f};
#pragma unroll
    for (int s = 0; s < 16; ++s)
#pragma unroll
        for (int r = 0; r < 4; ++r)
            mx[r] = fmaxf(mx[r], c[s][r]);
#pragma unroll
    for (int off = 1; off <= 8; off <<= 1)
#pragma unroll
        for (int r = 0; r < 4; ++r)
            mx[r] = fmaxf(mx[r], __shfl_xor(mx[r], off, 64));
    if (n16 == 0)
#pragma unroll
        for (int r = 0; r < 4; ++r) redbuf[0][w][quad * 4 + r] = mx[r];
    __syncthreads();
#pragma unroll
    for (int r = 0; r < 4; ++r) {
        const int row = quad * 4 + r;
        float m = redbuf[0][0][row];
        m = fmaxf(m, redbuf[0][1][row]);
        m = fmaxf(m, redbuf[0][2][row]);
        m = fmaxf(m, redbuf[0][3][row]);
        mx[r] = m;
    }

    float sm[4] = {0.f, 0.f, 0.f, 0.f};
#pragma unroll
    for (int s = 0; s < 16; ++s)
#pragma unroll
        for (int r = 0; r < 4; ++r) {
            float e = __expf(c[s][r] - mx[r]);
            c[s][r] = e;
            sm[r] += e;
        }
#pragma unroll
    for (int off = 1; off <= 8; off <<= 1)
#pragma unroll
        for (int r = 0; r < 4; ++r)
            sm[r] += __shfl_xor(sm[r], off, 64);
    if (n16 == 0)
#pragma unroll
        for (int r = 0; r < 4; ++r) redbuf[1][w][quad * 4 + r] = sm[r];
    __syncthreads();
    float inv[4];
#pragma unroll
    for (int r = 0; r < 4; ++r) {
        const int row = quad * 4 + r;
        inv[r] = 1.f / (redbuf[1][0][row] + redbuf[1][1][row] +
                        redbuf[1][2][row] + redbuf[1][3][row]);
    }

    // write attention (fp32) + P (bf16 to LDS for AV)
    float* abase = attn + ((size_t)bh * 1024 + qb * 16) * 1024;
#pragma unroll
    for (int s = 0; s < 16; ++s)
#pragma unroll
        for (int r = 0; r < 4; ++r) {
            const float a = c[s][r] * inv[r];
            const int row = quad * 4 + r;
            const int key = s * 64 + w * 16 + n16;
            abase[(size_t)row * 1024 + key] = a;
            Plds[row][key] = f2bf(a);
        }
    __syncthreads();    // P handoff (cross-wave columns)

    // ---- Phase 3: AV, wave-private dbuf staging, barrier-free ----
    f32x4 o = zero4;
    const unsigned short* vwbase = vt + (size_t)bh * 65536 +
                                   (size_t)(w * 16) * 1024;
    {
        uint4 r0 = *(const uint4*)(vwbase + (size_t)prow * 1024 + poff);
        uint4 r1 = *(const uint4*)(vwbase + (size_t)(prow + 8) * 1024 + poff);
        *(uint4*)&KVw[w][0][prow][poff]     = r0;
        *(uint4*)&KVw[w][0][prow + 8][poff] = r1;
    }
    for (int s = 0; s < 16; ++s) {
        uint4 n0, n1;
        if (s < 15) {
            const unsigned short* p = vwbase + (s + 1) * 64;
            n0 = *(const uint4*)(p + (size_t)prow * 1024 + poff);
            n1 = *(const uint4*)(p + (size_t)(prow + 8) * 1024 + poff);
        }
        const int pb = s & 1;
#pragma unroll
        for (int kk = 0; kk < 2; ++kk) {
            bf16x8 pf = ld_frag(&Plds[n16][s * 64 + kk * 32 + quad * 8]);
            bf16x8 vf = ld_frag(&KVw[w][pb][n16][kk * 32 + quad * 8]);
            o = MFMA16(pf, vf, o);
        }
        if (s < 15) {
            *(uint4*)&KVw[w][pb ^ 1][prow][poff]     = n0;
            *(uint4*)&KVw[w][pb ^ 1][prow + 8][poff] = n1;
        }
    }

#pragma unroll
    for (int r = 0; r < 4; ++r) {
        const int row = quad * 4 + r;
        values[(size_t)(b * 1024 + qb * 16 + row) * 1024 + h * 64 + w * 16 + n16] =
            f2bf(o[r]);
    }
}

// ---------------------------------------------------------------------------
extern "C" void kernel_launch(void* const* d_in, const int* in_sizes, int n_in,
                              void* d_out, int out_size, void* d_ws, size_t ws_size,
                              hipStream_t stream)
{
    const float* x     = (const float*)d_in[0];   // [4,1024,1024]
    const float* W_qkv = (const float*)d_in[1];   // [1024,3072]
    const float* b_qkv = (const float*)d_in[2];   // [3072]
    const float* W_o   = (const float*)d_in[3];   // [1024,1024]
    const float* b_o   = (const float*)d_in[4];   // [1024]

    float* o_out    = (float*)d_out;                          // [4096,1024] fp32
    float* attn_out = o_out + (size_t)B_ * S_ * D_;           // [64,1024,1024] fp32

    const size_t M1 = 1ull << 20;
    unsigned short* ws      = (unsigned short*)d_ws;
    unsigned short* x_bf    = ws;                 // 4M  [4096][1024]
    unsigned short* wqkvt   = ws + 4 * M1;        // 3M  [3072][1024]
    unsigned short* wot     = ws + 7 * M1;        // 1M  [1024][1024]
    unsigned short* qkbuf   = ws + 8 * M1;        // 8M  [4096][2048]
    unsigned short* vtbuf   = ws + 16 * M1;       // 4M  [64][64][1024]
    unsigned short* valbuf  = ws + 20 * M1;       // 4M  [4096][1024] (vnat, then values)

    preprocess<<<4096 + 768 + 256, 256, 0, stream>>>(
        x, x_bf, W_qkv, wqkvt, W_o, wot);

    gemm_bf16<0><<<dim3(3072 / 128, 4096 / 128), 256, 0, stream>>>(
        x_bf, wqkvt, b_qkv, qkbuf, valbuf, nullptr, 1024, 3072);

    transpose_v_bf16<<<dim3(S_ / 64, B_ * H_), 256, 0, stream>>>(valbuf, vtbuf);

    attn_fused<<<dim3(S_ / 16, B_ * H_), 256, 0, stream>>>(
        qkbuf, vtbuf, attn_out, valbuf);

    gemm_bf16<1><<<dim3(1024 / 128, 4096 / 128), 256, 0, stream>>>(
        valbuf, wot, b_o, nullptr, nullptr, o_out, 1024, 1024);
}

// Round 8
// 443.075 us; speedup vs baseline: 1.2386x; 1.2386x over previous
//
#include <hip/hip_runtime.h>

#define B_   4
#define S_   1024
#define D_   1024
#define H_   16
#define HD_  64

typedef __bf16 bf16_t;
typedef __attribute__((ext_vector_type(8))) __bf16 bf16x8;
typedef __attribute__((ext_vector_type(4))) float f32x4;

#define MFMA16(a, b, c) __builtin_amdgcn_mfma_f32_16x16x32_bf16((a), (b), (c), 0, 0, 0)

__device__ inline unsigned short f2bf(float f) {
    unsigned int u = __builtin_bit_cast(unsigned int, f);
    u += 0x7FFFu + ((u >> 16) & 1u);   // RNE
    return (unsigned short)(u >> 16);
}

__device__ inline bf16x8 ld_frag(const unsigned short* p) {
    uint4 u = *(const uint4*)p;
    return __builtin_bit_cast(bf16x8, u);
}

// ---------------------------------------------------------------------------
// Fused preprocessing (single launch, flattened 1D grid):
//   blocks [0, 4096)          : x fp32 -> bf16 (one float4/thread)
//   blocks [4096, 4096+768)   : W_qkv [1024][3072] -> wqkvt [3072][1024] bf16
//   blocks [4864, 4864+256)   : W_o   [1024][1024] -> wot   [1024][1024] bf16
// ---------------------------------------------------------------------------
__global__ __launch_bounds__(256) void preprocess(
    const float* __restrict__ x,     unsigned short* __restrict__ x_bf,
    const float* __restrict__ W_qkv, unsigned short* __restrict__ wqkvt,
    const float* __restrict__ W_o,   unsigned short* __restrict__ wot)
{
    __shared__ float T[64][65];
    const int tid = threadIdx.x;
    int bid = blockIdx.x;

    if (bid < 4096) {
        const size_t idx = (size_t)bid * 256 + tid;
        float4 v = *(const float4*)(x + idx * 4);
        ushort4 r;
        r.x = f2bf(v.x); r.y = f2bf(v.y); r.z = f2bf(v.z); r.w = f2bf(v.w);
        *(ushort4*)(x_bf + idx * 4) = r;
        return;
    }
    bid -= 4096;
    const float* in; unsigned short* out; int N, bx, by;
    if (bid < 768) { in = W_qkv; out = wqkvt; N = 3072; bx = bid % 48; by = bid / 48; }
    else { bid -= 768; in = W_o; out = wot; N = 1024; bx = bid % 16; by = bid / 16; }
    const int K = 1024;
    const int k0 = by * 64, n0 = bx * 64;
#pragma unroll
    for (int i = 0; i < 4; ++i) {
        int c = tid + i * 256;
        int row = c >> 4, col = (c & 15) << 2;
        float4 v = *(const float4*)(in + (size_t)(k0 + row) * N + n0 + col);
        T[row][col + 0] = v.x; T[row][col + 1] = v.y;
        T[row][col + 2] = v.z; T[row][col + 3] = v.w;
    }
    __syncthreads();
#pragma unroll
    for (int i = 0; i < 4; ++i) {
        int c = tid + i * 256;
        int nr = c >> 4, kc = (c & 15) << 2;
        ushort4 r;
        r.x = f2bf(T[kc + 0][nr]); r.y = f2bf(T[kc + 1][nr]);
        r.z = f2bf(T[kc + 2][nr]); r.w = f2bf(T[kc + 3][nr]);
        *(ushort4*)(out + (size_t)(n0 + nr) * K + k0 + kc) = r;
    }
}

// ---------------------------------------------------------------------------
// bf16 transpose of V into per-(b,h) key-major layout:
// v [4096][1024] (col = h*64+dim)  ->  vt [bh][dim][key].
// Grid (S/64, B*H), 256 threads.
// ---------------------------------------------------------------------------
__global__ __launch_bounds__(256) void transpose_v_bf16(
    const unsigned short* __restrict__ v,
    unsigned short* __restrict__ vt)
{
    __shared__ unsigned short T[64][65];
    const int tid = threadIdx.x;
    const int kt = blockIdx.x, bh = blockIdx.y;
    const int b = bh >> 4, h = bh & 15;
#pragma unroll
    for (int i = 0; i < 2; ++i) {
        const int c = tid + i * 256;
        const int key = c >> 3, off = (c & 7) << 3;
        uint4 u = *(const uint4*)(v + (size_t)(b * 1024 + kt * 64 + key) * 1024 + h * 64 + off);
        union { uint4 u4; unsigned short us[8]; } uu; uu.u4 = u;
#pragma unroll
        for (int t = 0; t < 8; ++t) T[key][off + t] = uu.us[t];
    }
    __syncthreads();
#pragma unroll
    for (int i = 0; i < 16; ++i) {
        const int c = tid + i * 256;          // 0..4095
        const int dim = c >> 6, key = c & 63;
        vt[((size_t)bh * 64 + dim) * 1024 + kt * 64 + key] = T[key][dim];
    }
}

// ---------------------------------------------------------------------------
// bf16 MFMA GEMM: C[M,N] = A[M,K] @ Bt[N,K]^T + bias.  (EXACT R5 structure —
// reg-staged uint4 with immediate ds_write into padded LDS [128][72];
// the R7 T14 stage-split regressed +97us, suspected VGPR spill.)
// MODE 0 (QKV): q (pre-scaled 1/8), k -> qk[row][head*128 + 0..127];
//               v -> vnat[row][head*64+dim] (coalesced; transposed later).
// MODE 1: fp32 out[M][N].
// ---------------------------------------------------------------------------
template<int MODE>
__global__ __launch_bounds__(256) void gemm_bf16(
    const unsigned short* __restrict__ A,
    const unsigned short* __restrict__ Bt,
    const float* __restrict__ bias,
    unsigned short* __restrict__ qk,
    unsigned short* __restrict__ vnat,
    float* __restrict__ out,
    int K, int N)
{
    __shared__ unsigned short Alds[128][72];
    __shared__ unsigned short Blds[128][72];
    const int tid  = threadIdx.x;
    const int l    = tid & 63, w = tid >> 6;
    const int wm   = w >> 1, wn = w & 1;
    const int quad = l >> 4, n16 = l & 15;
    const int bm = blockIdx.y * 128, bn = blockIdx.x * 128;

    const f32x4 zero4 = {0.f, 0.f, 0.f, 0.f};
    f32x4 acc[4][4];
#pragma unroll
    for (int i = 0; i < 4; ++i)
#pragma unroll
        for (int j = 0; j < 4; ++j) acc[i][j] = zero4;

    for (int k0 = 0; k0 < K; k0 += 64) {
#pragma unroll
        for (int i = 0; i < 4; ++i) {
            int c = tid + i * 256;
            int row = c >> 3, off = (c & 7) << 3;
            *(uint4*)&Alds[row][off] = *(const uint4*)(A + (size_t)(bm + row) * K + k0 + off);
            *(uint4*)&Blds[row][off] = *(const uint4*)(Bt + (size_t)(bn + row) * K + k0 + off);
        }
        __syncthreads();
#pragma unroll
        for (int kk = 0; kk < 2; ++kk) {
            const int kc = kk * 32 + quad * 8;
            bf16x8 af[4], bfv[4];
#pragma unroll
            for (int i = 0; i < 4; ++i) af[i]  = ld_frag(&Alds[wm * 64 + i * 16 + n16][kc]);
#pragma unroll
            for (int j = 0; j < 4; ++j) bfv[j] = ld_frag(&Blds[wn * 64 + j * 16 + n16][kc]);
#pragma unroll
            for (int i = 0; i < 4; ++i)
#pragma unroll
                for (int j = 0; j < 4; ++j)
                    acc[i][j] = MFMA16(af[i], bfv[j], acc[i][j]);
        }
        __syncthreads();
    }

    // epilogue
#pragma unroll
    for (int j = 0; j < 4; ++j) {
        const int col0 = bn + wn * 64 + j * 16;
        const int col  = col0 + n16;
        const float bv = bias ? bias[col] : 0.f;
        if (MODE == 0) {
            const int head = col0 / 192;
            const int rem  = col0 % 192;
            if (rem < 128) {
                // q columns (rem<64) carry the 1/sqrt(hd) logit scale so
                // attn_fused skips the per-logit multiply (exact in bf16).
                const float sc = (rem < 64) ? 0.125f : 1.0f;
#pragma unroll
                for (int i = 0; i < 4; ++i)
#pragma unroll
                    for (int r = 0; r < 4; ++r) {
                        int row = bm + wm * 64 + i * 16 + quad * 4 + r;
                        qk[(size_t)row * 2048 + head * 128 + rem + n16] =
                            f2bf((acc[i][j][r] + bv) * sc);
                    }
            } else {
                const int dcol = head * 64 + (rem - 128) + n16;
#pragma unroll
                for (int i = 0; i < 4; ++i)
#pragma unroll
                    for (int r = 0; r < 4; ++r) {
                        int row = bm + wm * 64 + i * 16 + quad * 4 + r;
                        vnat[(size_t)row * 1024 + dcol] = f2bf(acc[i][j][r] + bv);
                    }
            }
        } else {
#pragma unroll
            for (int i = 0; i < 4; ++i)
#pragma unroll
                for (int r = 0; r < 4; ++r) {
                    int row = bm + wm * 64 + i * 16 + quad * 4 + r;
                    out[(size_t)row * N + col] = acc[i][j][r] + bv;
                }
        }
    }
}

// ---------------------------------------------------------------------------
// Fused attention (EXACT R5 session-best structure): per block = 16 Q-rows
// of one (b,h). 4 waves. Wave-private K/V staging (wave w consumes only
// rows/dims w*16..+15), phases 1/3 barrier-free (in-wave lgkmcnt ordering).
// Depth-1 pipelined: load(s+1)->regs, ds_read+MFMA(s), ds_write(s+1).
// Barriers: 2 (softmax reductions) + 1 (P handoff). Grid (S/16, B*H).
// ---------------------------------------------------------------------------
__global__ __launch_bounds__(256) void attn_fused(
    const unsigned short* __restrict__ qk,   // [4096][2048]
    const unsigned short* __restrict__ vt,   // [64][64][1024]
    float* __restrict__ attn,                // [64][1024][1024]
    unsigned short* __restrict__ values)     // [4096][1024]
{
    __shared__ unsigned short KVw[4][2][16][72];   // [wave][buf][row][col]
    __shared__ unsigned short Plds[16][1032];
    __shared__ float redbuf[2][4][16];

    const int qb = blockIdx.x, bh = blockIdx.y;
    const int b = bh >> 4, h = bh & 15;
    const int tid = threadIdx.x, l = tid & 63, w = tid >> 6;
    const int quad = l >> 4, n16 = l & 15;

    const int prow = l >> 3;            // 0..7
    const int poff = (l & 7) << 3;      // 0..56 (ushort col)

    // preload Q A-frags (q already scaled by 1/8 in gemm<0> epilogue)
    bf16x8 qf[2];
    {
        const unsigned short* qbase =
            qk + (size_t)(b * 1024 + qb * 16 + n16) * 2048 + h * 128 + quad * 8;
        qf[0] = ld_frag(qbase);
        qf[1] = ld_frag(qbase + 32);
    }

    const f32x4 zero4 = {0.f, 0.f, 0.f, 0.f};
    f32x4 c[16];
#pragma unroll
    for (int s = 0; s < 16; ++s) c[s] = zero4;

    // ---- Phase 1: QK^T, wave-private dbuf staging, barrier-free ----
    const unsigned short* kwbase =
        qk + (size_t)(b * 1024 + w * 16) * 2048 + h * 128 + 64;
    {
        uint4 r0 = *(const uint4*)(kwbase + (size_t)prow * 2048 + poff);
        uint4 r1 = *(const uint4*)(kwbase + (size_t)(prow + 8) * 2048 + poff);
        *(uint4*)&KVw[w][0][prow][poff]     = r0;
        *(uint4*)&KVw[w][0][prow + 8][poff] = r1;
    }
    for (int s = 0; s < 16; ++s) {
        uint4 n0, n1;
        if (s < 15) {
            const unsigned short* p = kwbase + (size_t)(s + 1) * 64 * 2048;
            n0 = *(const uint4*)(p + (size_t)prow * 2048 + poff);
            n1 = *(const uint4*)(p + (size_t)(prow + 8) * 2048 + poff);
        }
        const int pb = s & 1;
        bf16x8 k0f = ld_frag(&KVw[w][pb][n16][quad * 8]);
        bf16x8 k1f = ld_frag(&KVw[w][pb][n16][32 + quad * 8]);
        c[s] = MFMA16(qf[0], k0f, c[s]);
        c[s] = MFMA16(qf[1], k1f, c[s]);
        if (s < 15) {
            *(uint4*)&KVw[w][pb ^ 1][prow][poff]     = n0;
            *(uint4*)&KVw[w][pb ^ 1][prow + 8][poff] = n1;
        }
    }

    // ---- Phase 2: softmax in registers ----
    float mx[4] = {-1e30f, -1e30f, -1e30f, -1e30f};
#pragma unroll
    for (int s = 0; s < 16; ++s)
#pragma unroll
        for (int r = 0; r < 4; ++r)
            mx[r] = fmaxf(mx[r], c[s][r]);
#pragma unroll
    for (int off = 1; off <= 8; off <<= 1)
#pragma unroll
        for (int r = 0; r < 4; ++r)
            mx[r] = fmaxf(mx[r], __shfl_xor(mx[r], off, 64));
    if (n16 == 0)
#pragma unroll
        for (int r = 0; r < 4; ++r) redbuf[0][w][quad * 4 + r] = mx[r];
    __syncthreads();
#pragma unroll
    for (int r = 0; r < 4; ++r) {
        const int row = quad * 4 + r;
        float m = redbuf[0][0][row];
        m = fmaxf(m, redbuf[0][1][row]);
        m = fmaxf(m, redbuf[0][2][row]);
        m = fmaxf(m, redbuf[0][3][row]);
        mx[r] = m;
    }

    float sm[4] = {0.f, 0.f, 0.f, 0.f};
#pragma unroll
    for (int s = 0; s < 16; ++s)
#pragma unroll
        for (int r = 0; r < 4; ++r) {
            float e = __expf(c[s][r] - mx[r]);
            c[s][r] = e;
            sm[r] += e;
        }
#pragma unroll
    for (int off = 1; off <= 8; off <<= 1)
#pragma unroll
        for (int r = 0; r < 4; ++r)
            sm[r] += __shfl_xor(sm[r], off, 64);
    if (n16 == 0)
#pragma unroll
        for (int r = 0; r < 4; ++r) redbuf[1][w][quad * 4 + r] = sm[r];
    __syncthreads();
    float inv[4];
#pragma unroll
    for (int r = 0; r < 4; ++r) {
        const int row = quad * 4 + r;
        inv[r] = 1.f / (redbuf[1][0][row] + redbuf[1][1][row] +
                        redbuf[1][2][row] + redbuf[1][3][row]);
    }

    // write attention (fp32) + P (bf16 to LDS for AV)
    float* abase = attn + ((size_t)bh * 1024 + qb * 16) * 1024;
#pragma unroll
    for (int s = 0; s < 16; ++s)
#pragma unroll
        for (int r = 0; r < 4; ++r) {
            const float a = c[s][r] * inv[r];
            const int row = quad * 4 + r;
            const int key = s * 64 + w * 16 + n16;
            abase[(size_t)row * 1024 + key] = a;
            Plds[row][key] = f2bf(a);
        }
    __syncthreads();    // P handoff (cross-wave columns)

    // ---- Phase 3: AV, wave-private dbuf staging, barrier-free ----
    f32x4 o = zero4;
    const unsigned short* vwbase = vt + (size_t)bh * 65536 +
                                   (size_t)(w * 16) * 1024;
    {
        uint4 r0 = *(const uint4*)(vwbase + (size_t)prow * 1024 + poff);
        uint4 r1 = *(const uint4*)(vwbase + (size_t)(prow + 8) * 1024 + poff);
        *(uint4*)&KVw[w][0][prow][poff]     = r0;
        *(uint4*)&KVw[w][0][prow + 8][poff] = r1;
    }
    for (int s = 0; s < 16; ++s) {
        uint4 n0, n1;
        if (s < 15) {
            const unsigned short* p = vwbase + (s + 1) * 64;
            n0 = *(const uint4*)(p + (size_t)prow * 1024 + poff);
            n1 = *(const uint4*)(p + (size_t)(prow + 8) * 1024 + poff);
        }
        const int pb = s & 1;
#pragma unroll
        for (int kk = 0; kk < 2; ++kk) {
            bf16x8 pf = ld_frag(&Plds[n16][s * 64 + kk * 32 + quad * 8]);
            bf16x8 vf = ld_frag(&KVw[w][pb][n16][kk * 32 + quad * 8]);
            o = MFMA16(pf, vf, o);
        }
        if (s < 15) {
            *(uint4*)&KVw[w][pb ^ 1][prow][poff]     = n0;
            *(uint4*)&KVw[w][pb ^ 1][prow + 8][poff] = n1;
        }
    }

#pragma unroll
    for (int r = 0; r < 4; ++r) {
        const int row = quad * 4 + r;
        values[(size_t)(b * 1024 + qb * 16 + row) * 1024 + h * 64 + w * 16 + n16] =
            f2bf(o[r]);
    }
}

// ---------------------------------------------------------------------------
extern "C" void kernel_launch(void* const* d_in, const int* in_sizes, int n_in,
                              void* d_out, int out_size, void* d_ws, size_t ws_size,
                              hipStream_t stream)
{
    const float* x     = (const float*)d_in[0];   // [4,1024,1024]
    const float* W_qkv = (const float*)d_in[1];   // [1024,3072]
    const float* b_qkv = (const float*)d_in[2];   // [3072]
    const float* W_o   = (const float*)d_in[3];   // [1024,1024]
    const float* b_o   = (const float*)d_in[4];   // [1024]

    float* o_out    = (float*)d_out;                          // [4096,1024] fp32
    float* attn_out = o_out + (size_t)B_ * S_ * D_;           // [64,1024,1024] fp32

    const size_t M1 = 1ull << 20;
    unsigned short* ws      = (unsigned short*)d_ws;
    unsigned short* x_bf    = ws;                 // 4M  [4096][1024]
    unsigned short* wqkvt   = ws + 4 * M1;        // 3M  [3072][1024]
    unsigned short* wot     = ws + 7 * M1;        // 1M  [1024][1024]
    unsigned short* qkbuf   = ws + 8 * M1;        // 8M  [4096][2048]
    unsigned short* vtbuf   = ws + 16 * M1;       // 4M  [64][64][1024]
    unsigned short* valbuf  = ws + 20 * M1;       // 4M  [4096][1024] (vnat, then values)

    preprocess<<<4096 + 768 + 256, 256, 0, stream>>>(
        x, x_bf, W_qkv, wqkvt, W_o, wot);

    gemm_bf16<0><<<dim3(3072 / 128, 4096 / 128), 256, 0, stream>>>(
        x_bf, wqkvt, b_qkv, qkbuf, valbuf, nullptr, 1024, 3072);

    transpose_v_bf16<<<dim3(S_ / 64, B_ * H_), 256, 0, stream>>>(valbuf, vtbuf);

    attn_fused<<<dim3(S_ / 16, B_ * H_), 256, 0, stream>>>(
        qkbuf, vtbuf, attn_out, valbuf);

    gemm_bf16<1><<<dim3(1024 / 128, 4096 / 128), 256, 0, stream>>>(
        valbuf, wot, b_o, nullptr, nullptr, o_out, 1024, 1024);
}

// Round 9
// 441.493 us; speedup vs baseline: 1.2431x; 1.0036x over previous
//
#include <hip/hip_runtime.h>

#define B_   4
#define S_   1024
#define D_   1024
#define H_   16
#define HD_  64

typedef __bf16 bf16_t;
typedef __attribute__((ext_vector_type(8))) __bf16 bf16x8;
typedef __attribute__((ext_vector_type(4))) float f32x4;

#define MFMA16(a, b, c) __builtin_amdgcn_mfma_f32_16x16x32_bf16((a), (b), (c), 0, 0, 0)

__device__ inline unsigned short f2bf(float f) {
    unsigned int u = __builtin_bit_cast(unsigned int, f);
    u += 0x7FFFu + ((u >> 16) & 1u);   // RNE
    return (unsigned short)(u >> 16);
}

__device__ inline bf16x8 ld_frag(const unsigned short* p) {
    uint4 u = *(const uint4*)p;
    return __builtin_bit_cast(bf16x8, u);
}

// ---------------------------------------------------------------------------
// Fused preprocessing (single launch, flattened 1D grid):
//   blocks [0, 4096)          : x fp32 -> bf16 (one float4/thread)
//   blocks [4096, 4096+768)   : W_qkv [1024][3072] -> wqkvt [3072][1024] bf16
//   blocks [4864, 4864+256)   : W_o   [1024][1024] -> wot   [1024][1024] bf16
// ---------------------------------------------------------------------------
__global__ __launch_bounds__(256) void preprocess(
    const float* __restrict__ x,     unsigned short* __restrict__ x_bf,
    const float* __restrict__ W_qkv, unsigned short* __restrict__ wqkvt,
    const float* __restrict__ W_o,   unsigned short* __restrict__ wot)
{
    __shared__ float T[64][65];
    const int tid = threadIdx.x;
    int bid = blockIdx.x;

    if (bid < 4096) {
        const size_t idx = (size_t)bid * 256 + tid;
        float4 v = *(const float4*)(x + idx * 4);
        ushort4 r;
        r.x = f2bf(v.x); r.y = f2bf(v.y); r.z = f2bf(v.z); r.w = f2bf(v.w);
        *(ushort4*)(x_bf + idx * 4) = r;
        return;
    }
    bid -= 4096;
    const float* in; unsigned short* out; int N, bx, by;
    if (bid < 768) { in = W_qkv; out = wqkvt; N = 3072; bx = bid % 48; by = bid / 48; }
    else { bid -= 768; in = W_o; out = wot; N = 1024; bx = bid % 16; by = bid / 16; }
    const int K = 1024;
    const int k0 = by * 64, n0 = bx * 64;
#pragma unroll
    for (int i = 0; i < 4; ++i) {
        int c = tid + i * 256;
        int row = c >> 4, col = (c & 15) << 2;
        float4 v = *(const float4*)(in + (size_t)(k0 + row) * N + n0 + col);
        T[row][col + 0] = v.x; T[row][col + 1] = v.y;
        T[row][col + 2] = v.z; T[row][col + 3] = v.w;
    }
    __syncthreads();
#pragma unroll
    for (int i = 0; i < 4; ++i) {
        int c = tid + i * 256;
        int nr = c >> 4, kc = (c & 15) << 2;
        ushort4 r;
        r.x = f2bf(T[kc + 0][nr]); r.y = f2bf(T[kc + 1][nr]);
        r.z = f2bf(T[kc + 2][nr]); r.w = f2bf(T[kc + 3][nr]);
        *(ushort4*)(out + (size_t)(n0 + nr) * K + k0 + kc) = r;
    }
}

// ---------------------------------------------------------------------------
// bf16 transpose of V into per-(b,h) key-major layout:
// v [4096][1024] (col = h*64+dim)  ->  vt [bh][dim][key].
// Grid (S/64, B*H), 256 threads.
// ---------------------------------------------------------------------------
__global__ __launch_bounds__(256) void transpose_v_bf16(
    const unsigned short* __restrict__ v,
    unsigned short* __restrict__ vt)
{
    __shared__ unsigned short T[64][65];
    const int tid = threadIdx.x;
    const int kt = blockIdx.x, bh = blockIdx.y;
    const int b = bh >> 4, h = bh & 15;
#pragma unroll
    for (int i = 0; i < 2; ++i) {
        const int c = tid + i * 256;
        const int key = c >> 3, off = (c & 7) << 3;
        uint4 u = *(const uint4*)(v + (size_t)(b * 1024 + kt * 64 + key) * 1024 + h * 64 + off);
        union { uint4 u4; unsigned short us[8]; } uu; uu.u4 = u;
#pragma unroll
        for (int t = 0; t < 8; ++t) T[key][off + t] = uu.us[t];
    }
    __syncthreads();
#pragma unroll
    for (int i = 0; i < 16; ++i) {
        const int c = tid + i * 256;          // 0..4095
        const int dim = c >> 6, key = c & 63;
        vt[((size_t)bh * 64 + dim) * 1024 + kt * 64 + key] = T[key][dim];
    }
}

// ---------------------------------------------------------------------------
// bf16 MFMA GEMM: C[M,N] = A[M,K] @ Bt[N,K]^T + bias.  (EXACT R5 structure —
// reg-staged uint4 with immediate ds_write into padded LDS [128][72].)
// MODE 0 (QKV): q (pre-scaled 1/8), k -> qk[row][head*128 + 0..127];
//               v -> vnat[row][head*64+dim] (coalesced; transposed later).
// MODE 1: fp32 out[M][N].
// ---------------------------------------------------------------------------
template<int MODE>
__global__ __launch_bounds__(256) void gemm_bf16(
    const unsigned short* __restrict__ A,
    const unsigned short* __restrict__ Bt,
    const float* __restrict__ bias,
    unsigned short* __restrict__ qk,
    unsigned short* __restrict__ vnat,
    float* __restrict__ out,
    int K, int N)
{
    __shared__ unsigned short Alds[128][72];
    __shared__ unsigned short Blds[128][72];
    const int tid  = threadIdx.x;
    const int l    = tid & 63, w = tid >> 6;
    const int wm   = w >> 1, wn = w & 1;
    const int quad = l >> 4, n16 = l & 15;
    const int bm = blockIdx.y * 128, bn = blockIdx.x * 128;

    const f32x4 zero4 = {0.f, 0.f, 0.f, 0.f};
    f32x4 acc[4][4];
#pragma unroll
    for (int i = 0; i < 4; ++i)
#pragma unroll
        for (int j = 0; j < 4; ++j) acc[i][j] = zero4;

    for (int k0 = 0; k0 < K; k0 += 64) {
#pragma unroll
        for (int i = 0; i < 4; ++i) {
            int c = tid + i * 256;
            int row = c >> 3, off = (c & 7) << 3;
            *(uint4*)&Alds[row][off] = *(const uint4*)(A + (size_t)(bm + row) * K + k0 + off);
            *(uint4*)&Blds[row][off] = *(const uint4*)(Bt + (size_t)(bn + row) * K + k0 + off);
        }
        __syncthreads();
#pragma unroll
        for (int kk = 0; kk < 2; ++kk) {
            const int kc = kk * 32 + quad * 8;
            bf16x8 af[4], bfv[4];
#pragma unroll
            for (int i = 0; i < 4; ++i) af[i]  = ld_frag(&Alds[wm * 64 + i * 16 + n16][kc]);
#pragma unroll
            for (int j = 0; j < 4; ++j) bfv[j] = ld_frag(&Blds[wn * 64 + j * 16 + n16][kc]);
#pragma unroll
            for (int i = 0; i < 4; ++i)
#pragma unroll
                for (int j = 0; j < 4; ++j)
                    acc[i][j] = MFMA16(af[i], bfv[j], acc[i][j]);
        }
        __syncthreads();
    }

    // epilogue
#pragma unroll
    for (int j = 0; j < 4; ++j) {
        const int col0 = bn + wn * 64 + j * 16;
        const int col  = col0 + n16;
        const float bv = bias ? bias[col] : 0.f;
        if (MODE == 0) {
            const int head = col0 / 192;
            const int rem  = col0 % 192;
            if (rem < 128) {
                // q columns (rem<64) carry the 1/sqrt(hd) logit scale so
                // attn_fused skips the per-logit multiply (exact in bf16).
                const float sc = (rem < 64) ? 0.125f : 1.0f;
#pragma unroll
                for (int i = 0; i < 4; ++i)
#pragma unroll
                    for (int r = 0; r < 4; ++r) {
                        int row = bm + wm * 64 + i * 16 + quad * 4 + r;
                        qk[(size_t)row * 2048 + head * 128 + rem + n16] =
                            f2bf((acc[i][j][r] + bv) * sc);
                    }
            } else {
                const int dcol = head * 64 + (rem - 128) + n16;
#pragma unroll
                for (int i = 0; i < 4; ++i)
#pragma unroll
                    for (int r = 0; r < 4; ++r) {
                        int row = bm + wm * 64 + i * 16 + quad * 4 + r;
                        vnat[(size_t)row * 1024 + dcol] = f2bf(acc[i][j][r] + bv);
                    }
            }
        } else {
#pragma unroll
            for (int i = 0; i < 4; ++i)
#pragma unroll
                for (int r = 0; r < 4; ++r) {
                    int row = bm + wm * 64 + i * 16 + quad * 4 + r;
                    out[(size_t)row * N + col] = acc[i][j][r] + bv;
                }
        }
    }
}

// ---------------------------------------------------------------------------
// Fused attention (R5 session-best inner structure, UNCHANGED) + T1 XCD
// swizzle: 1D grid 4096; bh = xcd*8 + chunk/64, qb = chunk%64 (bijective,
// xcd = flat&7 matches round-robin dispatch). All 64 qb-blocks of one (b,h)
// land on ONE XCD -> its 256KB K/V slice is fetched into one L2, and the
// concurrent per-XCD KV working set drops ~4MB -> ~512KB.
// ---------------------------------------------------------------------------
__global__ __launch_bounds__(256) void attn_fused(
    const unsigned short* __restrict__ qk,   // [4096][2048]
    const unsigned short* __restrict__ vt,   // [64][64][1024]
    float* __restrict__ attn,                // [64][1024][1024]
    unsigned short* __restrict__ values)     // [4096][1024]
{
    __shared__ unsigned short KVw[4][2][16][72];   // [wave][buf][row][col]
    __shared__ unsigned short Plds[16][1032];
    __shared__ float redbuf[2][4][16];

    // XCD-aware block swizzle (T1): keep each (b,h) on a single XCD.
    const int flat = blockIdx.x;
    const int xcd = flat & 7, chunk = flat >> 3;
    const int bh = xcd * 8 + (chunk >> 6);
    const int qb = chunk & 63;
    const int b = bh >> 4, h = bh & 15;
    const int tid = threadIdx.x, l = tid & 63, w = tid >> 6;
    const int quad = l >> 4, n16 = l & 15;

    const int prow = l >> 3;            // 0..7
    const int poff = (l & 7) << 3;      // 0..56 (ushort col)

    // preload Q A-frags (q already scaled by 1/8 in gemm<0> epilogue)
    bf16x8 qf[2];
    {
        const unsigned short* qbase =
            qk + (size_t)(b * 1024 + qb * 16 + n16) * 2048 + h * 128 + quad * 8;
        qf[0] = ld_frag(qbase);
        qf[1] = ld_frag(qbase + 32);
    }

    const f32x4 zero4 = {0.f, 0.f, 0.f, 0.f};
    f32x4 c[16];
#pragma unroll
    for (int s = 0; s < 16; ++s) c[s] = zero4;

    // ---- Phase 1: QK^T, wave-private dbuf staging, barrier-free ----
    const unsigned short* kwbase =
        qk + (size_t)(b * 1024 + w * 16) * 2048 + h * 128 + 64;
    {
        uint4 r0 = *(const uint4*)(kwbase + (size_t)prow * 2048 + poff);
        uint4 r1 = *(const uint4*)(kwbase + (size_t)(prow + 8) * 2048 + poff);
        *(uint4*)&KVw[w][0][prow][poff]     = r0;
        *(uint4*)&KVw[w][0][prow + 8][poff] = r1;
    }
    for (int s = 0; s < 16; ++s) {
        uint4 n0, n1;
        if (s < 15) {
            const unsigned short* p = kwbase + (size_t)(s + 1) * 64 * 2048;
            n0 = *(const uint4*)(p + (size_t)prow * 2048 + poff);
            n1 = *(const uint4*)(p + (size_t)(prow + 8) * 2048 + poff);
        }
        const int pb = s & 1;
        bf16x8 k0f = ld_frag(&KVw[w][pb][n16][quad * 8]);
        bf16x8 k1f = ld_frag(&KVw[w][pb][n16][32 + quad * 8]);
        c[s] = MFMA16(qf[0], k0f, c[s]);
        c[s] = MFMA16(qf[1], k1f, c[s]);
        if (s < 15) {
            *(uint4*)&KVw[w][pb ^ 1][prow][poff]     = n0;
            *(uint4*)&KVw[w][pb ^ 1][prow + 8][poff] = n1;
        }
    }

    // ---- Phase 2: softmax in registers ----
    float mx[4] = {-1e30f, -1e30f, -1e30f, -1e30f};
#pragma unroll
    for (int s = 0; s < 16; ++s)
#pragma unroll
        for (int r = 0; r < 4; ++r)
            mx[r] = fmaxf(mx[r], c[s][r]);
#pragma unroll
    for (int off = 1; off <= 8; off <<= 1)
#pragma unroll
        for (int r = 0; r < 4; ++r)
            mx[r] = fmaxf(mx[r], __shfl_xor(mx[r], off, 64));
    if (n16 == 0)
#pragma unroll
        for (int r = 0; r < 4; ++r) redbuf[0][w][quad * 4 + r] = mx[r];
    __syncthreads();
#pragma unroll
    for (int r = 0; r < 4; ++r) {
        const int row = quad * 4 + r;
        float m = redbuf[0][0][row];
        m = fmaxf(m, redbuf[0][1][row]);
        m = fmaxf(m, redbuf[0][2][row]);
        m = fmaxf(m, redbuf[0][3][row]);
        mx[r] = m;
    }

    float sm[4] = {0.f, 0.f, 0.f, 0.f};
#pragma unroll
    for (int s = 0; s < 16; ++s)
#pragma unroll
        for (int r = 0; r < 4; ++r) {
            float e = __expf(c[s][r] - mx[r]);
            c[s][r] = e;
            sm[r] += e;
        }
#pragma unroll
    for (int off = 1; off <= 8; off <<= 1)
#pragma unroll
        for (int r = 0; r < 4; ++r)
            sm[r] += __shfl_xor(sm[r], off, 64);
    if (n16 == 0)
#pragma unroll
        for (int r = 0; r < 4; ++r) redbuf[1][w][quad * 4 + r] = sm[r];
    __syncthreads();
    float inv[4];
#pragma unroll
    for (int r = 0; r < 4; ++r) {
        const int row = quad * 4 + r;
        inv[r] = 1.f / (redbuf[1][0][row] + redbuf[1][1][row] +
                        redbuf[1][2][row] + redbuf[1][3][row]);
    }

    // write attention (fp32) + P (bf16 to LDS for AV)
    float* abase = attn + ((size_t)bh * 1024 + qb * 16) * 1024;
#pragma unroll
    for (int s = 0; s < 16; ++s)
#pragma unroll
        for (int r = 0; r < 4; ++r) {
            const float a = c[s][r] * inv[r];
            const int row = quad * 4 + r;
            const int key = s * 64 + w * 16 + n16;
            abase[(size_t)row * 1024 + key] = a;
            Plds[row][key] = f2bf(a);
        }
    __syncthreads();    // P handoff (cross-wave columns)

    // ---- Phase 3: AV, wave-private dbuf staging, barrier-free ----
    f32x4 o = zero4;
    const unsigned short* vwbase = vt + (size_t)bh * 65536 +
                                   (size_t)(w * 16) * 1024;
    {
        uint4 r0 = *(const uint4*)(vwbase + (size_t)prow * 1024 + poff);
        uint4 r1 = *(const uint4*)(vwbase + (size_t)(prow + 8) * 1024 + poff);
        *(uint4*)&KVw[w][0][prow][poff]     = r0;
        *(uint4*)&KVw[w][0][prow + 8][poff] = r1;
    }
    for (int s = 0; s < 16; ++s) {
        uint4 n0, n1;
        if (s < 15) {
            const unsigned short* p = vwbase + (s + 1) * 64;
            n0 = *(const uint4*)(p + (size_t)prow * 1024 + poff);
            n1 = *(const uint4*)(p + (size_t)(prow + 8) * 1024 + poff);
        }
        const int pb = s & 1;
#pragma unroll
        for (int kk = 0; kk < 2; ++kk) {
            bf16x8 pf = ld_frag(&Plds[n16][s * 64 + kk * 32 + quad * 8]);
            bf16x8 vf = ld_frag(&KVw[w][pb][n16][kk * 32 + quad * 8]);
            o = MFMA16(pf, vf, o);
        }
        if (s < 15) {
            *(uint4*)&KVw[w][pb ^ 1][prow][poff]     = n0;
            *(uint4*)&KVw[w][pb ^ 1][prow + 8][poff] = n1;
        }
    }

#pragma unroll
    for (int r = 0; r < 4; ++r) {
        const int row = quad * 4 + r;
        values[(size_t)(b * 1024 + qb * 16 + row) * 1024 + h * 64 + w * 16 + n16] =
            f2bf(o[r]);
    }
}

// ---------------------------------------------------------------------------
extern "C" void kernel_launch(void* const* d_in, const int* in_sizes, int n_in,
                              void* d_out, int out_size, void* d_ws, size_t ws_size,
                              hipStream_t stream)
{
    const float* x     = (const float*)d_in[0];   // [4,1024,1024]
    const float* W_qkv = (const float*)d_in[1];   // [1024,3072]
    const float* b_qkv = (const float*)d_in[2];   // [3072]
    const float* W_o   = (const float*)d_in[3];   // [1024,1024]
    const float* b_o   = (const float*)d_in[4];   // [1024]

    float* o_out    = (float*)d_out;                          // [4096,1024] fp32
    float* attn_out = o_out + (size_t)B_ * S_ * D_;           // [64,1024,1024] fp32

    const size_t M1 = 1ull << 20;
    unsigned short* ws      = (unsigned short*)d_ws;
    unsigned short* x_bf    = ws;                 // 4M  [4096][1024]
    unsigned short* wqkvt   = ws + 4 * M1;        // 3M  [3072][1024]
    unsigned short* wot     = ws + 7 * M1;        // 1M  [1024][1024]
    unsigned short* qkbuf   = ws + 8 * M1;        // 8M  [4096][2048]
    unsigned short* vtbuf   = ws + 16 * M1;       // 4M  [64][64][1024]
    unsigned short* valbuf  = ws + 20 * M1;       // 4M  [4096][1024] (vnat, then values)

    preprocess<<<4096 + 768 + 256, 256, 0, stream>>>(
        x, x_bf, W_qkv, wqkvt, W_o, wot);

    gemm_bf16<0><<<dim3(3072 / 128, 4096 / 128), 256, 0, stream>>>(
        x_bf, wqkvt, b_qkv, qkbuf, valbuf, nullptr, 1024, 3072);

    transpose_v_bf16<<<dim3(S_ / 64, B_ * H_), 256, 0, stream>>>(valbuf, vtbuf);

    attn_fused<<<4096, 256, 0, stream>>>(
        qkbuf, vtbuf, attn_out, valbuf);

    gemm_bf16<1><<<dim3(1024 / 128, 4096 / 128), 256, 0, stream>>>(
        valbuf, wot, b_o, nullptr, nullptr, o_out, 1024, 1024);
}

// Round 10
// 425.584 us; speedup vs baseline: 1.2895x; 1.0374x over previous
//
#include <hip/hip_runtime.h>

#define B_   4
#define S_   1024
#define D_   1024
#define H_   16
#define HD_  64

typedef __bf16 bf16_t;
typedef __attribute__((ext_vector_type(8))) __bf16 bf16x8;
typedef __attribute__((ext_vector_type(4))) float f32x4;

#define MFMA16(a, b, c) __builtin_amdgcn_mfma_f32_16x16x32_bf16((a), (b), (c), 0, 0, 0)

__device__ inline unsigned short f2bf(float f) {
    unsigned int u = __builtin_bit_cast(unsigned int, f);
    u += 0x7FFFu + ((u >> 16) & 1u);   // RNE
    return (unsigned short)(u >> 16);
}

__device__ inline bf16x8 ld_frag(const unsigned short* p) {
    uint4 u = *(const uint4*)p;
    return __builtin_bit_cast(bf16x8, u);
}

// ---------------------------------------------------------------------------
// Fused preprocessing (single launch, flattened 1D grid):
//   blocks [0, 4096)          : x fp32 -> bf16 (one float4/thread)
//   blocks [4096, 4096+768)   : W_qkv [1024][3072] -> wqkvt [3072][1024] bf16
//   blocks [4864, 4864+256)   : W_o   [1024][1024] -> wot   [1024][1024] bf16
// ---------------------------------------------------------------------------
__global__ __launch_bounds__(256) void preprocess(
    const float* __restrict__ x,     unsigned short* __restrict__ x_bf,
    const float* __restrict__ W_qkv, unsigned short* __restrict__ wqkvt,
    const float* __restrict__ W_o,   unsigned short* __restrict__ wot)
{
    __shared__ float T[64][65];
    const int tid = threadIdx.x;
    int bid = blockIdx.x;

    if (bid < 4096) {
        const size_t idx = (size_t)bid * 256 + tid;
        float4 v = *(const float4*)(x + idx * 4);
        ushort4 r;
        r.x = f2bf(v.x); r.y = f2bf(v.y); r.z = f2bf(v.z); r.w = f2bf(v.w);
        *(ushort4*)(x_bf + idx * 4) = r;
        return;
    }
    bid -= 4096;
    const float* in; unsigned short* out; int N, bx, by;
    if (bid < 768) { in = W_qkv; out = wqkvt; N = 3072; bx = bid % 48; by = bid / 48; }
    else { bid -= 768; in = W_o; out = wot; N = 1024; bx = bid % 16; by = bid / 16; }
    const int K = 1024;
    const int k0 = by * 64, n0 = bx * 64;
#pragma unroll
    for (int i = 0; i < 4; ++i) {
        int c = tid + i * 256;
        int row = c >> 4, col = (c & 15) << 2;
        float4 v = *(const float4*)(in + (size_t)(k0 + row) * N + n0 + col);
        T[row][col + 0] = v.x; T[row][col + 1] = v.y;
        T[row][col + 2] = v.z; T[row][col + 3] = v.w;
    }
    __syncthreads();
#pragma unroll
    for (int i = 0; i < 4; ++i) {
        int c = tid + i * 256;
        int nr = c >> 4, kc = (c & 15) << 2;
        ushort4 r;
        r.x = f2bf(T[kc + 0][nr]); r.y = f2bf(T[kc + 1][nr]);
        r.z = f2bf(T[kc + 2][nr]); r.w = f2bf(T[kc + 3][nr]);
        *(ushort4*)(out + (size_t)(n0 + nr) * K + k0 + kc) = r;
    }
}

// ---------------------------------------------------------------------------
// bf16 transpose of V into per-(b,h) key-major layout:
// v [4096][1024] (col = h*64+dim)  ->  vt [bh][dim][key].
// Grid (S/64, B*H), 256 threads.
// ---------------------------------------------------------------------------
__global__ __launch_bounds__(256) void transpose_v_bf16(
    const unsigned short* __restrict__ v,
    unsigned short* __restrict__ vt)
{
    __shared__ unsigned short T[64][65];
    const int tid = threadIdx.x;
    const int kt = blockIdx.x, bh = blockIdx.y;
    const int b = bh >> 4, h = bh & 15;
#pragma unroll
    for (int i = 0; i < 2; ++i) {
        const int c = tid + i * 256;
        const int key = c >> 3, off = (c & 7) << 3;
        uint4 u = *(const uint4*)(v + (size_t)(b * 1024 + kt * 64 + key) * 1024 + h * 64 + off);
        union { uint4 u4; unsigned short us[8]; } uu; uu.u4 = u;
#pragma unroll
        for (int t = 0; t < 8; ++t) T[key][off + t] = uu.us[t];
    }
    __syncthreads();
#pragma unroll
    for (int i = 0; i < 16; ++i) {
        const int c = tid + i * 256;          // 0..4095
        const int dim = c >> 6, key = c & 63;
        vt[((size_t)bh * 64 + dim) * 1024 + kt * 64 + key] = T[key][dim];
    }
}

// ---------------------------------------------------------------------------
// bf16 MFMA GEMM: C[M,N] = A[M,K] @ Bt[N,K]^T + bias.  (EXACT R5 structure —
// reg-staged uint4 with immediate ds_write into padded LDS [128][72].)
// MODE 0 (QKV): q (pre-scaled 1/8), k -> qk[row][head*128 + 0..127];
//               v -> vnat[row][head*64+dim] (coalesced; transposed later).
// MODE 1: fp32 out[M][N] via NONTEMPORAL stores (o is never re-read).
// ---------------------------------------------------------------------------
template<int MODE>
__global__ __launch_bounds__(256) void gemm_bf16(
    const unsigned short* __restrict__ A,
    const unsigned short* __restrict__ Bt,
    const float* __restrict__ bias,
    unsigned short* __restrict__ qk,
    unsigned short* __restrict__ vnat,
    float* __restrict__ out,
    int K, int N)
{
    __shared__ unsigned short Alds[128][72];
    __shared__ unsigned short Blds[128][72];
    const int tid  = threadIdx.x;
    const int l    = tid & 63, w = tid >> 6;
    const int wm   = w >> 1, wn = w & 1;
    const int quad = l >> 4, n16 = l & 15;
    const int bm = blockIdx.y * 128, bn = blockIdx.x * 128;

    const f32x4 zero4 = {0.f, 0.f, 0.f, 0.f};
    f32x4 acc[4][4];
#pragma unroll
    for (int i = 0; i < 4; ++i)
#pragma unroll
        for (int j = 0; j < 4; ++j) acc[i][j] = zero4;

    for (int k0 = 0; k0 < K; k0 += 64) {
#pragma unroll
        for (int i = 0; i < 4; ++i) {
            int c = tid + i * 256;
            int row = c >> 3, off = (c & 7) << 3;
            *(uint4*)&Alds[row][off] = *(const uint4*)(A + (size_t)(bm + row) * K + k0 + off);
            *(uint4*)&Blds[row][off] = *(const uint4*)(Bt + (size_t)(bn + row) * K + k0 + off);
        }
        __syncthreads();
#pragma unroll
        for (int kk = 0; kk < 2; ++kk) {
            const int kc = kk * 32 + quad * 8;
            bf16x8 af[4], bfv[4];
#pragma unroll
            for (int i = 0; i < 4; ++i) af[i]  = ld_frag(&Alds[wm * 64 + i * 16 + n16][kc]);
#pragma unroll
            for (int j = 0; j < 4; ++j) bfv[j] = ld_frag(&Blds[wn * 64 + j * 16 + n16][kc]);
#pragma unroll
            for (int i = 0; i < 4; ++i)
#pragma unroll
                for (int j = 0; j < 4; ++j)
                    acc[i][j] = MFMA16(af[i], bfv[j], acc[i][j]);
        }
        __syncthreads();
    }

    // epilogue
#pragma unroll
    for (int j = 0; j < 4; ++j) {
        const int col0 = bn + wn * 64 + j * 16;
        const int col  = col0 + n16;
        const float bv = bias ? bias[col] : 0.f;
        if (MODE == 0) {
            const int head = col0 / 192;
            const int rem  = col0 % 192;
            if (rem < 128) {
                // q columns (rem<64) carry the 1/sqrt(hd) logit scale so
                // attn_fused skips the per-logit multiply (exact in bf16).
                const float sc = (rem < 64) ? 0.125f : 1.0f;
#pragma unroll
                for (int i = 0; i < 4; ++i)
#pragma unroll
                    for (int r = 0; r < 4; ++r) {
                        int row = bm + wm * 64 + i * 16 + quad * 4 + r;
                        qk[(size_t)row * 2048 + head * 128 + rem + n16] =
                            f2bf((acc[i][j][r] + bv) * sc);
                    }
            } else {
                const int dcol = head * 64 + (rem - 128) + n16;
#pragma unroll
                for (int i = 0; i < 4; ++i)
#pragma unroll
                    for (int r = 0; r < 4; ++r) {
                        int row = bm + wm * 64 + i * 16 + quad * 4 + r;
                        vnat[(size_t)row * 1024 + dcol] = f2bf(acc[i][j][r] + bv);
                    }
            }
        } else {
#pragma unroll
            for (int i = 0; i < 4; ++i)
#pragma unroll
                for (int r = 0; r < 4; ++r) {
                    int row = bm + wm * 64 + i * 16 + quad * 4 + r;
                    __builtin_nontemporal_store(acc[i][j][r] + bv,
                                                &out[(size_t)row * N + col]);
                }
        }
    }
}

// ---------------------------------------------------------------------------
// Fused attention (R5 inner structure + T1 XCD swizzle, UNCHANGED) with
// NONTEMPORAL stores for the 256MB fp32 attention output (write-once,
// never re-read -> keep it out of L2 so K/V + valbuf reuse survives).
// ---------------------------------------------------------------------------
__global__ __launch_bounds__(256) void attn_fused(
    const unsigned short* __restrict__ qk,   // [4096][2048]
    const unsigned short* __restrict__ vt,   // [64][64][1024]
    float* __restrict__ attn,                // [64][1024][1024]
    unsigned short* __restrict__ values)     // [4096][1024]
{
    __shared__ unsigned short KVw[4][2][16][72];   // [wave][buf][row][col]
    __shared__ unsigned short Plds[16][1032];
    __shared__ float redbuf[2][4][16];

    // XCD-aware block swizzle (T1): keep each (b,h) on a single XCD.
    const int flat = blockIdx.x;
    const int xcd = flat & 7, chunk = flat >> 3;
    const int bh = xcd * 8 + (chunk >> 6);
    const int qb = chunk & 63;
    const int b = bh >> 4, h = bh & 15;
    const int tid = threadIdx.x, l = tid & 63, w = tid >> 6;
    const int quad = l >> 4, n16 = l & 15;

    const int prow = l >> 3;            // 0..7
    const int poff = (l & 7) << 3;      // 0..56 (ushort col)

    // preload Q A-frags (q already scaled by 1/8 in gemm<0> epilogue)
    bf16x8 qf[2];
    {
        const unsigned short* qbase =
            qk + (size_t)(b * 1024 + qb * 16 + n16) * 2048 + h * 128 + quad * 8;
        qf[0] = ld_frag(qbase);
        qf[1] = ld_frag(qbase + 32);
    }

    const f32x4 zero4 = {0.f, 0.f, 0.f, 0.f};
    f32x4 c[16];
#pragma unroll
    for (int s = 0; s < 16; ++s) c[s] = zero4;

    // ---- Phase 1: QK^T, wave-private dbuf staging, barrier-free ----
    const unsigned short* kwbase =
        qk + (size_t)(b * 1024 + w * 16) * 2048 + h * 128 + 64;
    {
        uint4 r0 = *(const uint4*)(kwbase + (size_t)prow * 2048 + poff);
        uint4 r1 = *(const uint4*)(kwbase + (size_t)(prow + 8) * 2048 + poff);
        *(uint4*)&KVw[w][0][prow][poff]     = r0;
        *(uint4*)&KVw[w][0][prow + 8][poff] = r1;
    }
    for (int s = 0; s < 16; ++s) {
        uint4 n0, n1;
        if (s < 15) {
            const unsigned short* p = kwbase + (size_t)(s + 1) * 64 * 2048;
            n0 = *(const uint4*)(p + (size_t)prow * 2048 + poff);
            n1 = *(const uint4*)(p + (size_t)(prow + 8) * 2048 + poff);
        }
        const int pb = s & 1;
        bf16x8 k0f = ld_frag(&KVw[w][pb][n16][quad * 8]);
        bf16x8 k1f = ld_frag(&KVw[w][pb][n16][32 + quad * 8]);
        c[s] = MFMA16(qf[0], k0f, c[s]);
        c[s] = MFMA16(qf[1], k1f, c[s]);
        if (s < 15) {
            *(uint4*)&KVw[w][pb ^ 1][prow][poff]     = n0;
            *(uint4*)&KVw[w][pb ^ 1][prow + 8][poff] = n1;
        }
    }

    // ---- Phase 2: softmax in registers ----
    float mx[4] = {-1e30f, -1e30f, -1e30f, -1e30f};
#pragma unroll
    for (int s = 0; s < 16; ++s)
#pragma unroll
        for (int r = 0; r < 4; ++r)
            mx[r] = fmaxf(mx[r], c[s][r]);
#pragma unroll
    for (int off = 1; off <= 8; off <<= 1)
#pragma unroll
        for (int r = 0; r < 4; ++r)
            mx[r] = fmaxf(mx[r], __shfl_xor(mx[r], off, 64));
    if (n16 == 0)
#pragma unroll
        for (int r = 0; r < 4; ++r) redbuf[0][w][quad * 4 + r] = mx[r];
    __syncthreads();
#pragma unroll
    for (int r = 0; r < 4; ++r) {
        const int row = quad * 4 + r;
        float m = redbuf[0][0][row];
        m = fmaxf(m, redbuf[0][1][row]);
        m = fmaxf(m, redbuf[0][2][row]);
        m = fmaxf(m, redbuf[0][3][row]);
        mx[r] = m;
    }

    float sm[4] = {0.f, 0.f, 0.f, 0.f};
#pragma unroll
    for (int s = 0; s < 16; ++s)
#pragma unroll
        for (int r = 0; r < 4; ++r) {
            float e = __expf(c[s][r] - mx[r]);
            c[s][r] = e;
            sm[r] += e;
        }
#pragma unroll
    for (int off = 1; off <= 8; off <<= 1)
#pragma unroll
        for (int r = 0; r < 4; ++r)
            sm[r] += __shfl_xor(sm[r], off, 64);
    if (n16 == 0)
#pragma unroll
        for (int r = 0; r < 4; ++r) redbuf[1][w][quad * 4 + r] = sm[r];
    __syncthreads();
    float inv[4];
#pragma unroll
    for (int r = 0; r < 4; ++r) {
        const int row = quad * 4 + r;
        inv[r] = 1.f / (redbuf[1][0][row] + redbuf[1][1][row] +
                        redbuf[1][2][row] + redbuf[1][3][row]);
    }

    // write attention (fp32, NONTEMPORAL) + P (bf16 to LDS for AV)
    float* abase = attn + ((size_t)bh * 1024 + qb * 16) * 1024;
#pragma unroll
    for (int s = 0; s < 16; ++s)
#pragma unroll
        for (int r = 0; r < 4; ++r) {
            const float a = c[s][r] * inv[r];
            const int row = quad * 4 + r;
            const int key = s * 64 + w * 16 + n16;
            __builtin_nontemporal_store(a, &abase[(size_t)row * 1024 + key]);
            Plds[row][key] = f2bf(a);
        }
    __syncthreads();    // P handoff (cross-wave columns)

    // ---- Phase 3: AV, wave-private dbuf staging, barrier-free ----
    f32x4 o = zero4;
    const unsigned short* vwbase = vt + (size_t)bh * 65536 +
                                   (size_t)(w * 16) * 1024;
    {
        uint4 r0 = *(const uint4*)(vwbase + (size_t)prow * 1024 + poff);
        uint4 r1 = *(const uint4*)(vwbase + (size_t)(prow + 8) * 1024 + poff);
        *(uint4*)&KVw[w][0][prow][poff]     = r0;
        *(uint4*)&KVw[w][0][prow + 8][poff] = r1;
    }
    for (int s = 0; s < 16; ++s) {
        uint4 n0, n1;
        if (s < 15) {
            const unsigned short* p = vwbase + (s + 1) * 64;
            n0 = *(const uint4*)(p + (size_t)prow * 1024 + poff);
            n1 = *(const uint4*)(p + (size_t)(prow + 8) * 1024 + poff);
        }
        const int pb = s & 1;
#pragma unroll
        for (int kk = 0; kk < 2; ++kk) {
            bf16x8 pf = ld_frag(&Plds[n16][s * 64 + kk * 32 + quad * 8]);
            bf16x8 vf = ld_frag(&KVw[w][pb][n16][kk * 32 + quad * 8]);
            o = MFMA16(pf, vf, o);
        }
        if (s < 15) {
            *(uint4*)&KVw[w][pb ^ 1][prow][poff]     = n0;
            *(uint4*)&KVw[w][pb ^ 1][prow + 8][poff] = n1;
        }
    }

#pragma unroll
    for (int r = 0; r < 4; ++r) {
        const int row = quad * 4 + r;
        values[(size_t)(b * 1024 + qb * 16 + row) * 1024 + h * 64 + w * 16 + n16] =
            f2bf(o[r]);
    }
}

// ---------------------------------------------------------------------------
extern "C" void kernel_launch(void* const* d_in, const int* in_sizes, int n_in,
                              void* d_out, int out_size, void* d_ws, size_t ws_size,
                              hipStream_t stream)
{
    const float* x     = (const float*)d_in[0];   // [4,1024,1024]
    const float* W_qkv = (const float*)d_in[1];   // [1024,3072]
    const float* b_qkv = (const float*)d_in[2];   // [3072]
    const float* W_o   = (const float*)d_in[3];   // [1024,1024]
    const float* b_o   = (const float*)d_in[4];   // [1024]

    float* o_out    = (float*)d_out;                          // [4096,1024] fp32
    float* attn_out = o_out + (size_t)B_ * S_ * D_;           // [64,1024,1024] fp32

    const size_t M1 = 1ull << 20;
    unsigned short* ws      = (unsigned short*)d_ws;
    unsigned short* x_bf    = ws;                 // 4M  [4096][1024]
    unsigned short* wqkvt   = ws + 4 * M1;        // 3M  [3072][1024]
    unsigned short* wot     = ws + 7 * M1;        // 1M  [1024][1024]
    unsigned short* qkbuf   = ws + 8 * M1;        // 8M  [4096][2048]
    unsigned short* vtbuf   = ws + 16 * M1;       // 4M  [64][64][1024]
    unsigned short* valbuf  = ws + 20 * M1;       // 4M  [4096][1024] (vnat, then values)

    preprocess<<<4096 + 768 + 256, 256, 0, stream>>>(
        x, x_bf, W_qkv, wqkvt, W_o, wot);

    gemm_bf16<0><<<dim3(3072 / 128, 4096 / 128), 256, 0, stream>>>(
        x_bf, wqkvt, b_qkv, qkbuf, valbuf, nullptr, 1024, 3072);

    transpose_v_bf16<<<dim3(S_ / 64, B_ * H_), 256, 0, stream>>>(valbuf, vtbuf);

    attn_fused<<<4096, 256, 0, stream>>>(
        qkbuf, vtbuf, attn_out, valbuf);

    gemm_bf16<1><<<dim3(1024 / 128, 4096 / 128), 256, 0, stream>>>(
        valbuf, wot, b_o, nullptr, nullptr, o_out, 1024, 1024);
}

// Round 12
// 423.570 us; speedup vs baseline: 1.2957x; 1.0048x over previous
//
#include <hip/hip_runtime.h>

#define B_   4
#define S_   1024
#define D_   1024
#define H_   16
#define HD_  64

typedef __bf16 bf16_t;
typedef __attribute__((ext_vector_type(8))) __bf16 bf16x8;
typedef __attribute__((ext_vector_type(4))) float f32x4;
typedef __attribute__((ext_vector_type(4))) unsigned int u32x4;

#define MFMA16(a, b, c) __builtin_amdgcn_mfma_f32_16x16x32_bf16((a), (b), (c), 0, 0, 0)

__device__ inline unsigned short f2bf(float f) {
    unsigned int u = __builtin_bit_cast(unsigned int, f);
    u += 0x7FFFu + ((u >> 16) & 1u);   // RNE
    return (unsigned short)(u >> 16);
}

__device__ inline bf16x8 ld_frag(const unsigned short* p) {
    uint4 u = *(const uint4*)p;
    return __builtin_bit_cast(bf16x8, u);
}

// NT 16B loads via ext_vector_type (HIP float4/uint4 are struct-wrapped and
// rejected by the builtin).
__device__ inline f32x4 nt_load_f4(const float* p) {
    return __builtin_nontemporal_load((const f32x4*)p);
}
__device__ inline u32x4 nt_load_u4(const unsigned short* p) {
    return __builtin_nontemporal_load((const u32x4*)p);
}

// ---------------------------------------------------------------------------
// Fused preprocessing (single launch, flattened 1D grid):
//   blocks [0, 4096)          : x fp32 -> bf16 (one float4/thread)
//   blocks [4096, 4096+768)   : W_qkv [1024][3072] -> wqkvt [3072][1024] bf16
//   blocks [4864, 4864+256)   : W_o   [1024][1024] -> wot   [1024][1024] bf16
// All fp32 inputs are read-once -> NONTEMPORAL loads (keep 64MB of dead
// lines out of L2/L3 so the bf16 working set survives into the GEMMs).
// ---------------------------------------------------------------------------
__global__ __launch_bounds__(256) void preprocess(
    const float* __restrict__ x,     unsigned short* __restrict__ x_bf,
    const float* __restrict__ W_qkv, unsigned short* __restrict__ wqkvt,
    const float* __restrict__ W_o,   unsigned short* __restrict__ wot)
{
    __shared__ float T[64][65];
    const int tid = threadIdx.x;
    int bid = blockIdx.x;

    if (bid < 4096) {
        const size_t idx = (size_t)bid * 256 + tid;
        f32x4 v = nt_load_f4(x + idx * 4);
        ushort4 r;
        r.x = f2bf(v.x); r.y = f2bf(v.y); r.z = f2bf(v.z); r.w = f2bf(v.w);
        *(ushort4*)(x_bf + idx * 4) = r;
        return;
    }
    bid -= 4096;
    const float* in; unsigned short* out; int N, bx, by;
    if (bid < 768) { in = W_qkv; out = wqkvt; N = 3072; bx = bid % 48; by = bid / 48; }
    else { bid -= 768; in = W_o; out = wot; N = 1024; bx = bid % 16; by = bid / 16; }
    const int K = 1024;
    const int k0 = by * 64, n0 = bx * 64;
#pragma unroll
    for (int i = 0; i < 4; ++i) {
        int c = tid + i * 256;
        int row = c >> 4, col = (c & 15) << 2;
        f32x4 v = nt_load_f4(in + (size_t)(k0 + row) * N + n0 + col);
        T[row][col + 0] = v.x; T[row][col + 1] = v.y;
        T[row][col + 2] = v.z; T[row][col + 3] = v.w;
    }
    __syncthreads();
#pragma unroll
    for (int i = 0; i < 4; ++i) {
        int c = tid + i * 256;
        int nr = c >> 4, kc = (c & 15) << 2;
        ushort4 r;
        r.x = f2bf(T[kc + 0][nr]); r.y = f2bf(T[kc + 1][nr]);
        r.z = f2bf(T[kc + 2][nr]); r.w = f2bf(T[kc + 3][nr]);
        *(ushort4*)(out + (size_t)(n0 + nr) * K + k0 + kc) = r;
    }
}

// ---------------------------------------------------------------------------
// bf16 transpose of V into per-(b,h) key-major layout:
// v [4096][1024] (col = h*64+dim)  ->  vt [bh][dim][key].
// v (vnat) is read exactly once here (then overwritten) -> NT load.
// Grid (S/64, B*H), 256 threads.
// ---------------------------------------------------------------------------
__global__ __launch_bounds__(256) void transpose_v_bf16(
    const unsigned short* __restrict__ v,
    unsigned short* __restrict__ vt)
{
    __shared__ unsigned short T[64][65];
    const int tid = threadIdx.x;
    const int kt = blockIdx.x, bh = blockIdx.y;
    const int b = bh >> 4, h = bh & 15;
#pragma unroll
    for (int i = 0; i < 2; ++i) {
        const int c = tid + i * 256;
        const int key = c >> 3, off = (c & 7) << 3;
        u32x4 u = nt_load_u4(v + (size_t)(b * 1024 + kt * 64 + key) * 1024 + h * 64 + off);
        union { u32x4 u4; unsigned short us[8]; } uu; uu.u4 = u;
#pragma unroll
        for (int t = 0; t < 8; ++t) T[key][off + t] = uu.us[t];
    }
    __syncthreads();
#pragma unroll
    for (int i = 0; i < 16; ++i) {
        const int c = tid + i * 256;          // 0..4095
        const int dim = c >> 6, key = c & 63;
        vt[((size_t)bh * 64 + dim) * 1024 + kt * 64 + key] = T[key][dim];
    }
}

// ---------------------------------------------------------------------------
// bf16 MFMA GEMM: C[M,N] = A[M,K] @ Bt[N,K]^T + bias.  (EXACT R5 structure —
// reg-staged uint4 with immediate ds_write into padded LDS [128][72].)
// MODE 0 (QKV): q (pre-scaled 1/8), k -> qk[row][head*128 + 0..127];
//               v -> vnat[row][head*64+dim] (coalesced; transposed later).
// MODE 1: fp32 out[M][N] via NONTEMPORAL stores (o is never re-read).
// ---------------------------------------------------------------------------
template<int MODE>
__global__ __launch_bounds__(256) void gemm_bf16(
    const unsigned short* __restrict__ A,
    const unsigned short* __restrict__ Bt,
    const float* __restrict__ bias,
    unsigned short* __restrict__ qk,
    unsigned short* __restrict__ vnat,
    float* __restrict__ out,
    int K, int N)
{
    __shared__ unsigned short Alds[128][72];
    __shared__ unsigned short Blds[128][72];
    const int tid  = threadIdx.x;
    const int l    = tid & 63, w = tid >> 6;
    const int wm   = w >> 1, wn = w & 1;
    const int quad = l >> 4, n16 = l & 15;
    const int bm = blockIdx.y * 128, bn = blockIdx.x * 128;

    const f32x4 zero4 = {0.f, 0.f, 0.f, 0.f};
    f32x4 acc[4][4];
#pragma unroll
    for (int i = 0; i < 4; ++i)
#pragma unroll
        for (int j = 0; j < 4; ++j) acc[i][j] = zero4;

    for (int k0 = 0; k0 < K; k0 += 64) {
#pragma unroll
        for (int i = 0; i < 4; ++i) {
            int c = tid + i * 256;
            int row = c >> 3, off = (c & 7) << 3;
            *(uint4*)&Alds[row][off] = *(const uint4*)(A + (size_t)(bm + row) * K + k0 + off);
            *(uint4*)&Blds[row][off] = *(const uint4*)(Bt + (size_t)(bn + row) * K + k0 + off);
        }
        __syncthreads();
#pragma unroll
        for (int kk = 0; kk < 2; ++kk) {
            const int kc = kk * 32 + quad * 8;
            bf16x8 af[4], bfv[4];
#pragma unroll
            for (int i = 0; i < 4; ++i) af[i]  = ld_frag(&Alds[wm * 64 + i * 16 + n16][kc]);
#pragma unroll
            for (int j = 0; j < 4; ++j) bfv[j] = ld_frag(&Blds[wn * 64 + j * 16 + n16][kc]);
#pragma unroll
            for (int i = 0; i < 4; ++i)
#pragma unroll
                for (int j = 0; j < 4; ++j)
                    acc[i][j] = MFMA16(af[i], bfv[j], acc[i][j]);
        }
        __syncthreads();
    }

    // epilogue
#pragma unroll
    for (int j = 0; j < 4; ++j) {
        const int col0 = bn + wn * 64 + j * 16;
        const int col  = col0 + n16;
        const float bv = bias ? bias[col] : 0.f;
        if (MODE == 0) {
            const int head = col0 / 192;
            const int rem  = col0 % 192;
            if (rem < 128) {
                // q columns (rem<64) carry the 1/sqrt(hd) logit scale so
                // attn_fused skips the per-logit multiply (exact in bf16).
                const float sc = (rem < 64) ? 0.125f : 1.0f;
#pragma unroll
                for (int i = 0; i < 4; ++i)
#pragma unroll
                    for (int r = 0; r < 4; ++r) {
                        int row = bm + wm * 64 + i * 16 + quad * 4 + r;
                        qk[(size_t)row * 2048 + head * 128 + rem + n16] =
                            f2bf((acc[i][j][r] + bv) * sc);
                    }
            } else {
                const int dcol = head * 64 + (rem - 128) + n16;
#pragma unroll
                for (int i = 0; i < 4; ++i)
#pragma unroll
                    for (int r = 0; r < 4; ++r) {
                        int row = bm + wm * 64 + i * 16 + quad * 4 + r;
                        vnat[(size_t)row * 1024 + dcol] = f2bf(acc[i][j][r] + bv);
                    }
            }
        } else {
#pragma unroll
            for (int i = 0; i < 4; ++i)
#pragma unroll
                for (int r = 0; r < 4; ++r) {
                    int row = bm + wm * 64 + i * 16 + quad * 4 + r;
                    __builtin_nontemporal_store(acc[i][j][r] + bv,
                                                &out[(size_t)row * N + col]);
                }
        }
    }
}

// ---------------------------------------------------------------------------
// Fused attention (R5 inner structure + T1 XCD swizzle, UNCHANGED) with
// NONTEMPORAL stores for the 256MB fp32 attention output (write-once,
// never re-read -> keep it out of L2 so K/V + valbuf reuse survives).
// NOTE: Q reads NOT marked NT — Q and K segments share 128B cachelines.
// ---------------------------------------------------------------------------
__global__ __launch_bounds__(256) void attn_fused(
    const unsigned short* __restrict__ qk,   // [4096][2048]
    const unsigned short* __restrict__ vt,   // [64][64][1024]
    float* __restrict__ attn,                // [64][1024][1024]
    unsigned short* __restrict__ values)     // [4096][1024]
{
    __shared__ unsigned short KVw[4][2][16][72];   // [wave][buf][row][col]
    __shared__ unsigned short Plds[16][1032];
    __shared__ float redbuf[2][4][16];

    // XCD-aware block swizzle (T1): keep each (b,h) on a single XCD.
    const int flat = blockIdx.x;
    const int xcd = flat & 7, chunk = flat >> 3;
    const int bh = xcd * 8 + (chunk >> 6);
    const int qb = chunk & 63;
    const int b = bh >> 4, h = bh & 15;
    const int tid = threadIdx.x, l = tid & 63, w = tid >> 6;
    const int quad = l >> 4, n16 = l & 15;

    const int prow = l >> 3;            // 0..7
    const int poff = (l & 7) << 3;      // 0..56 (ushort col)

    // preload Q A-frags (q already scaled by 1/8 in gemm<0> epilogue)
    bf16x8 qf[2];
    {
        const unsigned short* qbase =
            qk + (size_t)(b * 1024 + qb * 16 + n16) * 2048 + h * 128 + quad * 8;
        qf[0] = ld_frag(qbase);
        qf[1] = ld_frag(qbase + 32);
    }

    const f32x4 zero4 = {0.f, 0.f, 0.f, 0.f};
    f32x4 c[16];
#pragma unroll
    for (int s = 0; s < 16; ++s) c[s] = zero4;

    // ---- Phase 1: QK^T, wave-private dbuf staging, barrier-free ----
    const unsigned short* kwbase =
        qk + (size_t)(b * 1024 + w * 16) * 2048 + h * 128 + 64;
    {
        uint4 r0 = *(const uint4*)(kwbase + (size_t)prow * 2048 + poff);
        uint4 r1 = *(const uint4*)(kwbase + (size_t)(prow + 8) * 2048 + poff);
        *(uint4*)&KVw[w][0][prow][poff]     = r0;
        *(uint4*)&KVw[w][0][prow + 8][poff] = r1;
    }
    for (int s = 0; s < 16; ++s) {
        uint4 n0, n1;
        if (s < 15) {
            const unsigned short* p = kwbase + (size_t)(s + 1) * 64 * 2048;
            n0 = *(const uint4*)(p + (size_t)prow * 2048 + poff);
            n1 = *(const uint4*)(p + (size_t)(prow + 8) * 2048 + poff);
        }
        const int pb = s & 1;
        bf16x8 k0f = ld_frag(&KVw[w][pb][n16][quad * 8]);
        bf16x8 k1f = ld_frag(&KVw[w][pb][n16][32 + quad * 8]);
        c[s] = MFMA16(qf[0], k0f, c[s]);
        c[s] = MFMA16(qf[1], k1f, c[s]);
        if (s < 15) {
            *(uint4*)&KVw[w][pb ^ 1][prow][poff]     = n0;
            *(uint4*)&KVw[w][pb ^ 1][prow + 8][poff] = n1;
        }
    }

    // ---- Phase 2: softmax in registers ----
    float mx[4] = {-1e30f, -1e30f, -1e30f, -1e30f};
#pragma unroll
    for (int s = 0; s < 16; ++s)
#pragma unroll
        for (int r = 0; r < 4; ++r)
            mx[r] = fmaxf(mx[r], c[s][r]);
#pragma unroll
    for (int off = 1; off <= 8; off <<= 1)
#pragma unroll
        for (int r = 0; r < 4; ++r)
            mx[r] = fmaxf(mx[r], __shfl_xor(mx[r], off, 64));
    if (n16 == 0)
#pragma unroll
        for (int r = 0; r < 4; ++r) redbuf[0][w][quad * 4 + r] = mx[r];
    __syncthreads();
#pragma unroll
    for (int r = 0; r < 4; ++r) {
        const int row = quad * 4 + r;
        float m = redbuf[0][0][row];
        m = fmaxf(m, redbuf[0][1][row]);
        m = fmaxf(m, redbuf[0][2][row]);
        m = fmaxf(m, redbuf[0][3][row]);
        mx[r] = m;
    }

    float sm[4] = {0.f, 0.f, 0.f, 0.f};
#pragma unroll
    for (int s = 0; s < 16; ++s)
#pragma unroll
        for (int r = 0; r < 4; ++r) {
            float e = __expf(c[s][r] - mx[r]);
            c[s][r] = e;
            sm[r] += e;
        }
#pragma unroll
    for (int off = 1; off <= 8; off <<= 1)
#pragma unroll
        for (int r = 0; r < 4; ++r)
            sm[r] += __shfl_xor(sm[r], off, 64);
    if (n16 == 0)
#pragma unroll
        for (int r = 0; r < 4; ++r) redbuf[1][w][quad * 4 + r] = sm[r];
    __syncthreads();
    float inv[4];
#pragma unroll
    for (int r = 0; r < 4; ++r) {
        const int row = quad * 4 + r;
        inv[r] = 1.f / (redbuf[1][0][row] + redbuf[1][1][row] +
                        redbuf[1][2][row] + redbuf[1][3][row]);
    }

    // write attention (fp32, NONTEMPORAL) + P (bf16 to LDS for AV)
    float* abase = attn + ((size_t)bh * 1024 + qb * 16) * 1024;
#pragma unroll
    for (int s = 0; s < 16; ++s)
#pragma unroll
        for (int r = 0; r < 4; ++r) {
            const float a = c[s][r] * inv[r];
            const int row = quad * 4 + r;
            const int key = s * 64 + w * 16 + n16;
            __builtin_nontemporal_store(a, &abase[(size_t)row * 1024 + key]);
            Plds[row][key] = f2bf(a);
        }
    __syncthreads();    // P handoff (cross-wave columns)

    // ---- Phase 3: AV, wave-private dbuf staging, barrier-free ----
    f32x4 o = zero4;
    const unsigned short* vwbase = vt + (size_t)bh * 65536 +
                                   (size_t)(w * 16) * 1024;
    {
        uint4 r0 = *(const uint4*)(vwbase + (size_t)prow * 1024 + poff);
        uint4 r1 = *(const uint4*)(vwbase + (size_t)(prow + 8) * 1024 + poff);
        *(uint4*)&KVw[w][0][prow][poff]     = r0;
        *(uint4*)&KVw[w][0][prow + 8][poff] = r1;
    }
    for (int s = 0; s < 16; ++s) {
        uint4 n0, n1;
        if (s < 15) {
            const unsigned short* p = vwbase + (s + 1) * 64;
            n0 = *(const uint4*)(p + (size_t)prow * 1024 + poff);
            n1 = *(const uint4*)(p + (size_t)(prow + 8) * 1024 + poff);
        }
        const int pb = s & 1;
#pragma unroll
        for (int kk = 0; kk < 2; ++kk) {
            bf16x8 pf = ld_frag(&Plds[n16][s * 64 + kk * 32 + quad * 8]);
            bf16x8 vf = ld_frag(&KVw[w][pb][n16][kk * 32 + quad * 8]);
            o = MFMA16(pf, vf, o);
        }
        if (s < 15) {
            *(uint4*)&KVw[w][pb ^ 1][prow][poff]     = n0;
            *(uint4*)&KVw[w][pb ^ 1][prow + 8][poff] = n1;
        }
    }

#pragma unroll
    for (int r = 0; r < 4; ++r) {
        const int row = quad * 4 + r;
        values[(size_t)(b * 1024 + qb * 16 + row) * 1024 + h * 64 + w * 16 + n16] =
            f2bf(o[r]);
    }
}

// ---------------------------------------------------------------------------
extern "C" void kernel_launch(void* const* d_in, const int* in_sizes, int n_in,
                              void* d_out, int out_size, void* d_ws, size_t ws_size,
                              hipStream_t stream)
{
    const float* x     = (const float*)d_in[0];   // [4,1024,1024]
    const float* W_qkv = (const float*)d_in[1];   // [1024,3072]
    const float* b_qkv = (const float*)d_in[2];   // [3072]
    const float* W_o   = (const float*)d_in[3];   // [1024,1024]
    const float* b_o   = (const float*)d_in[4];   // [1024]

    float* o_out    = (float*)d_out;                          // [4096,1024] fp32
    float* attn_out = o_out + (size_t)B_ * S_ * D_;           // [64,1024,1024] fp32

    const size_t M1 = 1ull << 20;
    unsigned short* ws      = (unsigned short*)d_ws;
    unsigned short* x_bf    = ws;                 // 4M  [4096][1024]
    unsigned short* wqkvt   = ws + 4 * M1;        // 3M  [3072][1024]
    unsigned short* wot     = ws + 7 * M1;        // 1M  [1024][1024]
    unsigned short* qkbuf   = ws + 8 * M1;        // 8M  [4096][2048]
    unsigned short* vtbuf   = ws + 16 * M1;       // 4M  [64][64][1024]
    unsigned short* valbuf  = ws + 20 * M1;       // 4M  [4096][1024] (vnat, then values)

    preprocess<<<4096 + 768 + 256, 256, 0, stream>>>(
        x, x_bf, W_qkv, wqkvt, W_o, wot);

    gemm_bf16<0><<<dim3(3072 / 128, 4096 / 128), 256, 0, stream>>>(
        x_bf, wqkvt, b_qkv, qkbuf, valbuf, nullptr, 1024, 3072);

    transpose_v_bf16<<<dim3(S_ / 64, B_ * H_), 256, 0, stream>>>(valbuf, vtbuf);

    attn_fused<<<4096, 256, 0, stream>>>(
        qkbuf, vtbuf, attn_out, valbuf);

    gemm_bf16<1><<<dim3(1024 / 128, 4096 / 128), 256, 0, stream>>>(
        valbuf, wot, b_o, nullptr, nullptr, o_out, 1024, 1024);
}